// Round 8
// baseline (328.888 us; speedup 1.0000x reference)
//
#include <hip/hip_runtime.h>
#include <hip/hip_bf16.h>
#include <hip/hip_cooperative_groups.h>
#include <stdint.h>

namespace cg = cooperative_groups;

typedef float  f32x4  __attribute__((ext_vector_type(4)));
typedef __bf16 bf16x4 __attribute__((ext_vector_type(4)));
typedef __bf16 bf16x8 __attribute__((ext_vector_type(8)));
typedef unsigned int u32x2 __attribute__((ext_vector_type(2)));
typedef unsigned int u32x4 __attribute__((ext_vector_type(4)));

#define AS1 __attribute__((address_space(1)))
#define AS3 __attribute__((address_space(3)))

__device__ __forceinline__ void async_load16(const void* g, void* lds) {
    __builtin_amdgcn_global_load_lds((const AS1 unsigned int*)g,
                                     (AS3 unsigned int*)lds, 16, 0, 0);
}

// ===========================================================================
// Fused cooperative kernel: 256 blocks x 512 threads (always co-resident:
// 8 waves/CU, <=256 VGPR, 32KB LDS). 4 phases with grid.sync between.
// ===========================================================================
__global__ __launch_bounds__(512) void fused_kernel(
    const float* __restrict__ x, const int* __restrict__ eos_idx,
    const float* __restrict__ q_emb, const float* __restrict__ wk,
    const float* __restrict__ bk, float* __restrict__ out_p,
    __bf16* __restrict__ qwT, float* __restrict__ Lg,
    float* __restrict__ partials, float* __restrict__ y)
{
    __shared__ char smem[32768];
    cg::grid_group gg = cg::this_grid();
    const int t = threadIdx.x, l = t & 63, w = t >> 6;
    const int bid = blockIdx.x;   // 0..255

    // ================= phase 0: qw[hs][k] (192 busy blocks) =================
    if (bid < 192) {
        float* qlds = (float*)smem;        // 256 f
        float* part = qlds + 256;          // 4096 f  [k 64][s 4][dseg 16]
        const int kc = bid % 12, h = bid / 12, k0 = kc * 64;
        if (t < 256) qlds[t] = q_emb[h * 256 + t] * 0.125f;  // scale 1/8
        __syncthreads();
        {
            const int dseg = t & 15, krow = t >> 4;  // 0..31
#pragma unroll
            for (int i = 0; i < 2; ++i) {
                const int k = i * 32 + krow;
                f32x4 wv = *(const f32x4*)&wk[(size_t)(k0 + k) * 1024 + h * 64 + dseg * 4];
#pragma unroll
                for (int s = 0; s < 4; ++s) {
                    float p = qlds[s * 64 + dseg * 4 + 0] * wv[0]
                            + qlds[s * 64 + dseg * 4 + 1] * wv[1]
                            + qlds[s * 64 + dseg * 4 + 2] * wv[2]
                            + qlds[s * 64 + dseg * 4 + 3] * wv[3];
                    part[k * 64 + s * 16 + dseg] = p;
                }
            }
        }
        __syncthreads();
        if (t < 256) {
            const int k = t >> 2, s = t & 3;
            const float* pp = &part[k * 64 + s * 16];
            float sum = 0.f;
#pragma unroll
            for (int j = 0; j < 16; ++j) sum += pp[j];
            qwT[(h * 4 + s) * 768 + k0 + k] = (__bf16)sum;
        }
    }
    __threadfence();
    gg.sync();

    // ============ phase 1: logits + partials (2 m-tiles per block) ==========
    for (int rep = 0; rep < 2; ++rep) {
        if (rep) __syncthreads();
        char* Bl = smem;           // 2 x 8 KB [col 64][k 64] bf16, XOR ((col&7)<<4)
        char* Al = smem + 16384;   // 2 x 8 KB [row 64][k 64] bf16, XOR ((row&7)<<4)
        const int tile = bid * 2 + rep;
        const int m0 = tile * 64;
        const int bb = m0 >> 10, n0 = m0 & 1023, chunk = (m0 >> 6) & 15;
        const int wm = (w >> 1) * 16, wh = (w & 1) * 32;
        f32x4 acc[2];
        acc[0] = (f32x4)0.f; acc[1] = (f32x4)0.f;
        const int Bcol = t >> 3, Bseg = t & 7;
        const __bf16* qsrc = qwT + Bcol * 768 + (Bseg ^ (Bcol & 7)) * 8;
        const int Arow = t >> 3;
        const float* xrow = &x[(size_t)(m0 + Arow) * 768 + (t & 7) * 8];
        const int Adst = (Arow * 128 + (t & 7) * 16) ^ ((Arow & 7) << 4);
        f32x4 av0, av1;

        async_load16(qsrc, Bl + t * 16);
        av0 = *(const f32x4*)(xrow);
        av1 = *(const f32x4*)(xrow + 4);
        {
            bf16x8 v;
            v[0] = (__bf16)av0[0]; v[1] = (__bf16)av0[1];
            v[2] = (__bf16)av0[2]; v[3] = (__bf16)av0[3];
            v[4] = (__bf16)av1[0]; v[5] = (__bf16)av1[1];
            v[6] = (__bf16)av1[2]; v[7] = (__bf16)av1[3];
            *(bf16x8*)(Al + Adst) = v;
        }
        asm volatile("s_waitcnt vmcnt(0)" ::: "memory");
        __syncthreads();

        int buf = 0;
        for (int step = 0; step < 12; ++step) {
            const int nbuf = buf ^ 1;
            const bool more = (step + 1) < 12;
            if (more) {
                const int kt = (step + 1) * 64;
                async_load16(qsrc + kt, Bl + nbuf * 8192 + t * 16);
                av0 = *(const f32x4*)(xrow + kt);
                av1 = *(const f32x4*)(xrow + kt + 4);
            }
#pragma unroll
            for (int kh = 0; kh < 2; ++kh) {
                const int u = kh * 4 + (l >> 4);
                const int arow = wm + (l & 15);
                bf16x8 af = *(const bf16x8*)(Al + buf * 8192 +
                                             ((arow * 128 + u * 16) ^ ((arow & 7) << 4)));
#pragma unroll
                for (int j = 0; j < 2; ++j) {
                    const int col = wh + j * 16 + (l & 15);
                    bf16x8 bfr = *(const bf16x8*)(Bl + buf * 8192 +
                                                  ((col * 128 + u * 16) ^ ((col & 7) << 4)));
                    acc[j] = __builtin_amdgcn_mfma_f32_16x16x32_bf16(af, bfr, acc[j], 0, 0, 0);
                }
            }
            if (more) {
                bf16x8 v;
                v[0] = (__bf16)av0[0]; v[1] = (__bf16)av0[1];
                v[2] = (__bf16)av0[2]; v[3] = (__bf16)av0[3];
                v[4] = (__bf16)av1[0]; v[5] = (__bf16)av1[1];
                v[6] = (__bf16)av1[2]; v[7] = (__bf16)av1[3];
                *(bf16x8*)(Al + nbuf * 8192 + Adst) = v;
            }
            asm volatile("s_waitcnt vmcnt(0)" ::: "memory");
            __syncthreads();
            buf = nbuf;
        }

        // epilogue: frags -> smem [hs 64][n 64] f32 -> mask, stats, store
#pragma unroll
        for (int j = 0; j < 2; ++j) {
            const int hs = wh + j * 16 + (l & 15);
            const int nb = wm + (l >> 4) * 4;
            *(f32x4*)(smem + ((hs * 256 + nb * 4) ^ ((hs & 7) << 4))) = acc[j];
        }
        __syncthreads();
        const int eosb = eos_idx[bb];
        const int hs = t >> 3, seg = t & 7;
        const int fH = (hs & 7) << 4;
        f32x4 v0 = *(const f32x4*)(smem + ((hs * 256 + seg * 32) ^ fH));
        f32x4 v1 = *(const f32x4*)(smem + ((hs * 256 + seg * 32 + 16) ^ fH));
        const int nbase = n0 + seg * 8;
        float mx = -INFINITY;
#pragma unroll
        for (int j = 0; j < 4; ++j) {
            if (nbase + j > eosb) v0[j] = -INFINITY;
            if (nbase + 4 + j > eosb) v1[j] = -INFINITY;
            mx = fmaxf(mx, fmaxf(v0[j], v1[j]));
        }
        *(f32x4*)&Lg[(size_t)bb * 65536 + hs * 1024 + nbase] = v0;
        *(f32x4*)&Lg[(size_t)bb * 65536 + hs * 1024 + nbase + 4] = v1;
#pragma unroll
        for (int off = 1; off < 8; off <<= 1) mx = fmaxf(mx, __shfl_xor(mx, off));
        float sl = 0.f;
        if (mx > -INFINITY) {
#pragma unroll
            for (int j = 0; j < 4; ++j) sl += __expf(v0[j] - mx) + __expf(v1[j] - mx);
        }
#pragma unroll
        for (int off = 1; off < 8; off <<= 1) sl += __shfl_xor(sl, off);
        if (seg == 0) {
            float2 st = {mx, sl};
            *(float2*)&partials[(size_t)(((bb * 16 + chunk) * 64) + hs) * 2] = st;
        }
    }
    __threadfence();
    gg.sync();

    // ========= phase 2: pv, 768 (b,kc,nh) units, 3 per block ==========
    for (int rep = 0; rep < 3; ++rep) {
        if (rep) __syncthreads();
        char* Pl = smem;           // 2 x 8 KB [hs 64][n 64] bf16, XOR ((row&7)<<4)
        char* Xl = smem + 16384;   // 2 x 8 KB [k 64][n 64] bf16, XOR fK
        const int u0 = bid + rep * 256;        // 0..767
        const int b = u0 / 24, rem = u0 % 24;
        const int kc = rem % 12, nh = rem / 12;
        const int k0 = kc * 64, nb0 = nh * 512;
        const int whs = (w & 1) * 32, wkk = ((w >> 1) & 1) * 32, wn = w >> 2;
        const float* Lgb = Lg + (size_t)b * 65536;
        const int xc = t & 63;
        const float* xb = x + (size_t)b * 786432 + k0 + xc;
        const int pr = t >> 3, pseg = t & 7;
        const int pn0 = ((pseg ^ (pr & 7)) * 8);
        const int fK = ((xc & 7) << 4) | (((xc >> 3) & 1) << 3);

        // combine softmax partials for row pr
        float mr, ir;
        {
            const float* pb = partials + (size_t)b * 2048;
            float m = -INFINITY;
#pragma unroll
            for (int c = 0; c < 16; ++c) m = fmaxf(m, pb[(c * 64 + pr) * 2]);
            float s = 0.f;
#pragma unroll
            for (int c = 0; c < 16; ++c) {
                float2 p0 = *(const float2*)&pb[(c * 64 + pr) * 2];
                s += p0.y * __expf(p0.x - m);
            }
            mr = m; ir = 1.0f / s;
        }

        f32x4 acc[2][2];
#pragma unroll
        for (int i = 0; i < 2; ++i)
#pragma unroll
            for (int j = 0; j < 2; ++j) acc[i][j] = (f32x4)0.f;

        auto PV_STAGE = [&](int bufb, int T) {
            f32x4 lo = *(const f32x4*)&Lgb[(size_t)pr * 1024 + nb0 + T * 64 + pn0];
            f32x4 hi = *(const f32x4*)&Lgb[(size_t)pr * 1024 + nb0 + T * 64 + pn0 + 4];
            bf16x8 pk;
#pragma unroll
            for (int j = 0; j < 4; ++j) pk[j]     = (__bf16)(__expf(lo[j] - mr) * ir);
#pragma unroll
            for (int j = 0; j < 4; ++j) pk[4 + j] = (__bf16)(__expf(hi[j] - mr) * ir);
            *(bf16x8*)(Pl + bufb * 8192 + t * 16) = pk;
            float xv[8];
#pragma unroll
            for (int j = 0; j < 8; ++j)
                xv[j] = xb[(size_t)(nb0 + T * 64 + w * 8 + j) * 768];
            bf16x4 va = {(__bf16)xv[0], (__bf16)xv[1], (__bf16)xv[2], (__bf16)xv[3]};
            bf16x4 vb = {(__bf16)xv[4], (__bf16)xv[5], (__bf16)xv[6], (__bf16)xv[7]};
            const int addr0 = xc * 128 + w * 16;
            *(bf16x4*)(Xl + bufb * 8192 + (addr0 ^ fK)) = va;
            *(bf16x4*)(Xl + bufb * 8192 + ((addr0 + 8) ^ fK)) = vb;
        };
        auto PV_COMPUTE = [&](int bufb) {
            const int u8 = wn * 4 + (l >> 4);
            bf16x8 af[2], bfr[2];
#pragma unroll
            for (int i = 0; i < 2; ++i) {
                const int prow = whs + i * 16 + (l & 15);
                af[i] = *(const bf16x8*)(Pl + bufb * 8192 +
                                         ((prow * 128 + u8 * 16) ^ ((prow & 7) << 4)));
            }
#pragma unroll
            for (int j = 0; j < 2; ++j) {
                const int kcol = wkk + j * 16 + (l & 15);
                const int fKc = ((kcol & 7) << 4) | (((kcol >> 3) & 1) << 3);
                const int addrA = kcol * 128 + wn * 64 + (l >> 4) * 16;
                u32x2 lo = *(const u32x2*)(Xl + bufb * 8192 + (addrA ^ fKc));
                u32x2 hi = *(const u32x2*)(Xl + bufb * 8192 + ((addrA + 8) ^ fKc));
                u32x4 uv = {lo[0], lo[1], hi[0], hi[1]};
                bfr[j] = __builtin_bit_cast(bf16x8, uv);
            }
#pragma unroll
            for (int i = 0; i < 2; ++i)
#pragma unroll
                for (int j = 0; j < 2; ++j)
                    acc[i][j] = __builtin_amdgcn_mfma_f32_16x16x32_bf16(
                        af[i], bfr[j], acc[i][j], 0, 0, 0);
        };

        PV_STAGE(0, 0);
        __syncthreads();
        int bufv = 0;
        for (int step = 0; step < 8; ++step) {
            if (step + 1 < 8) PV_STAGE(bufv ^ 1, step + 1);
            PV_COMPUTE(bufv);
            __syncthreads();
            bufv ^= 1;
        }

        // merge wn pairs in LDS [hs 64][k 64] f32, then store y half
        if (wn == 0) {
#pragma unroll
            for (int i = 0; i < 2; ++i)
#pragma unroll
                for (int j = 0; j < 2; ++j)
#pragma unroll
                    for (int r = 0; r < 4; ++r) {
                        const int hs2 = whs + i * 16 + (l >> 4) * 4 + r;
                        const int kcol = wkk + j * 16 + (l & 15);
                        *(float*)(smem + ((hs2 * 256 + kcol * 4) ^ ((hs2 & 7) << 4))) = acc[i][j][r];
                    }
        }
        __syncthreads();
        if (wn == 1) {
#pragma unroll
            for (int i = 0; i < 2; ++i)
#pragma unroll
                for (int j = 0; j < 2; ++j)
#pragma unroll
                    for (int r = 0; r < 4; ++r) {
                        const int hs2 = whs + i * 16 + (l >> 4) * 4 + r;
                        const int kcol = wkk + j * 16 + (l & 15);
                        float* p = (float*)(smem + ((hs2 * 256 + kcol * 4) ^ ((hs2 & 7) << 4)));
                        *p += acc[i][j][r];
                    }
        }
        __syncthreads();
        {
            const int hs3 = t >> 3, seg3 = t & 7, fH3 = (hs3 & 7) << 4;
            f32x4 o0 = *(const f32x4*)(smem + ((hs3 * 256 + seg3 * 32) ^ fH3));
            f32x4 o1 = *(const f32x4*)(smem + ((hs3 * 256 + seg3 * 32 + 16) ^ fH3));
            float* yh = y + (size_t)nh * 1572864;
            *(f32x4*)&yh[(size_t)(b * 64 + hs3) * 768 + k0 + seg3 * 8] = o0;
            *(f32x4*)&yh[(size_t)(b * 64 + hs3) * 768 + k0 + seg3 * 8 + 4] = o1;
        }
    }
    __threadfence();
    gg.sync();

    // ================= phase 3: out (512 units, 2 per block) ================
    for (int rep = 0; rep < 2; ++rep) {
        if (rep) __syncthreads();
        float* ylds = (float*)smem;          // 4 x 768 f = 12 KB
        float* red  = (float*)smem + 3072;   // 2048 f = 8 KB
        const int u0 = bid + rep * 256;
        const int h = u0 >> 5, b = u0 & 31;
#pragma unroll
        for (int r = 0; r < 4; ++r) {
            const size_t base = (size_t)(b * 64 + h * 4 + r) * 768;
            ylds[r * 768 + t] = y[base + t] + y[base + t + 1572864];
            if (t < 256) ylds[r * 768 + 512 + t] = y[base + 512 + t] + y[base + 512 + t + 1572864];
        }
        __syncthreads();
        const int kp = t >> 6, d = t & 63;
        float a4[4] = {0.f, 0.f, 0.f, 0.f};
        for (int i = 0; i < 24; ++i) {
            const int k = kp * 96 + i * 4;
            const float wv0 = wk[(size_t)(k + 0) * 1024 + h * 64 + d];
            const float wv1 = wk[(size_t)(k + 1) * 1024 + h * 64 + d];
            const float wv2 = wk[(size_t)(k + 2) * 1024 + h * 64 + d];
            const float wv3 = wk[(size_t)(k + 3) * 1024 + h * 64 + d];
#pragma unroll
            for (int r = 0; r < 4; ++r) {
                f32x4 yv = *(const f32x4*)&ylds[r * 768 + k];
                a4[r] += yv[0] * wv0 + yv[1] * wv1 + yv[2] * wv2 + yv[3] * wv3;
            }
        }
#pragma unroll
        for (int r = 0; r < 4; ++r) red[(r * 64 + d) * 8 + kp] = a4[r];
        __syncthreads();
        if (t < 256) {
            const int r = t >> 6, dd = t & 63;
            f32x4 p0 = *(const f32x4*)&red[(r * 64 + dd) * 8];
            f32x4 p1 = *(const f32x4*)&red[(r * 64 + dd) * 8 + 4];
            const float s = p0[0] + p0[1] + p0[2] + p0[3] +
                            p1[0] + p1[1] + p1[2] + p1[3] + bk[h * 64 + dd];
            out_p[(size_t)(b * 64 + h * 4 + r) * 64 + dd] = s;
        }
    }
}

// ===========================================================================
// Fallback path: validated 4-kernel pipeline (round-6), same ws layout.
// ===========================================================================
__global__ __launch_bounds__(256) void qw_kernel(const float* __restrict__ q_emb,
                                                 const float* __restrict__ wk,
                                                 __bf16* __restrict__ qwT) {
    __shared__ float qlds[256];
    __shared__ float part[4096];
    const int t = threadIdx.x;
    const int kc = blockIdx.x, h = blockIdx.y, k0 = kc * 64;
    qlds[t] = q_emb[h * 256 + t] * 0.125f;
    __syncthreads();
    const int dseg = t & 15, krow = t >> 4;
#pragma unroll
    for (int i = 0; i < 4; ++i) {
        const int k = i * 16 + krow;
        f32x4 wv = *(const f32x4*)&wk[(size_t)(k0 + k) * 1024 + h * 64 + dseg * 4];
#pragma unroll
        for (int s = 0; s < 4; ++s) {
            float p = qlds[s * 64 + dseg * 4 + 0] * wv[0]
                    + qlds[s * 64 + dseg * 4 + 1] * wv[1]
                    + qlds[s * 64 + dseg * 4 + 2] * wv[2]
                    + qlds[s * 64 + dseg * 4 + 3] * wv[3];
            part[k * 64 + s * 16 + dseg] = p;
        }
    }
    __syncthreads();
    const int k = t >> 2, s = t & 3;
    const float* pp = &part[k * 64 + s * 16];
    float sum = 0.f;
#pragma unroll
    for (int j = 0; j < 16; ++j) sum += pp[j];
    qwT[(h * 4 + s) * 768 + k0 + k] = (__bf16)sum;
}

__global__ __launch_bounds__(512) void logits_kernel(const float* __restrict__ x,
                                                     const __bf16* __restrict__ qwT,
                                                     const int* __restrict__ eos_idx,
                                                     float* __restrict__ Lg,
                                                     float* __restrict__ partials) {
    __shared__ char smem[32768];
    char* Bl = smem;
    char* Al = smem + 16384;
    const int t = threadIdx.x, l = t & 63, w = t >> 6;
    const int m0 = blockIdx.x * 64;
    const int bb = m0 >> 10, n0 = m0 & 1023, chunk = (m0 >> 6) & 15;
    const int wm = (w >> 1) * 16, wh = (w & 1) * 32;
    f32x4 acc[2];
    acc[0] = (f32x4)0.f; acc[1] = (f32x4)0.f;
    const int Bcol = t >> 3, Bseg = t & 7;
    const __bf16* qsrc = qwT + Bcol * 768 + (Bseg ^ (Bcol & 7)) * 8;
    const int Arow = t >> 3;
    const float* xrow = &x[(size_t)(m0 + Arow) * 768 + (t & 7) * 8];
    const int Adst = (Arow * 128 + (t & 7) * 16) ^ ((Arow & 7) << 4);
    f32x4 av0, av1;
    async_load16(qsrc, Bl + t * 16);
    av0 = *(const f32x4*)(xrow);
    av1 = *(const f32x4*)(xrow + 4);
    {
        bf16x8 v;
        v[0] = (__bf16)av0[0]; v[1] = (__bf16)av0[1];
        v[2] = (__bf16)av0[2]; v[3] = (__bf16)av0[3];
        v[4] = (__bf16)av1[0]; v[5] = (__bf16)av1[1];
        v[6] = (__bf16)av1[2]; v[7] = (__bf16)av1[3];
        *(bf16x8*)(Al + Adst) = v;
    }
    asm volatile("s_waitcnt vmcnt(0)" ::: "memory");
    __syncthreads();
    int buf = 0;
    for (int step = 0; step < 12; ++step) {
        const int nbuf = buf ^ 1;
        const bool more = (step + 1) < 12;
        if (more) {
            const int kt = (step + 1) * 64;
            async_load16(qsrc + kt, Bl + nbuf * 8192 + t * 16);
            av0 = *(const f32x4*)(xrow + kt);
            av1 = *(const f32x4*)(xrow + kt + 4);
        }
#pragma unroll
        for (int kh = 0; kh < 2; ++kh) {
            const int u = kh * 4 + (l >> 4);
            const int arow = wm + (l & 15);
            bf16x8 af = *(const bf16x8*)(Al + buf * 8192 +
                                         ((arow * 128 + u * 16) ^ ((arow & 7) << 4)));
#pragma unroll
            for (int j = 0; j < 2; ++j) {
                const int col = wh + j * 16 + (l & 15);
                bf16x8 bfr = *(const bf16x8*)(Bl + buf * 8192 +
                                              ((col * 128 + u * 16) ^ ((col & 7) << 4)));
                acc[j] = __builtin_amdgcn_mfma_f32_16x16x32_bf16(af, bfr, acc[j], 0, 0, 0);
            }
        }
        if (more) {
            bf16x8 v;
            v[0] = (__bf16)av0[0]; v[1] = (__bf16)av0[1];
            v[2] = (__bf16)av0[2]; v[3] = (__bf16)av0[3];
            v[4] = (__bf16)av1[0]; v[5] = (__bf16)av1[1];
            v[6] = (__bf16)av1[2]; v[7] = (__bf16)av1[3];
            *(bf16x8*)(Al + nbuf * 8192 + Adst) = v;
        }
        asm volatile("s_waitcnt vmcnt(0)" ::: "memory");
        __syncthreads();
        buf = nbuf;
    }
#pragma unroll
    for (int j = 0; j < 2; ++j) {
        const int hs = wh + j * 16 + (l & 15);
        const int nb = wm + (l >> 4) * 4;
        *(f32x4*)(smem + ((hs * 256 + nb * 4) ^ ((hs & 7) << 4))) = acc[j];
    }
    __syncthreads();
    const int eosb = eos_idx[bb];
    const int hs = t >> 3, seg = t & 7;
    const int fH = (hs & 7) << 4;
    f32x4 v0 = *(const f32x4*)(smem + ((hs * 256 + seg * 32) ^ fH));
    f32x4 v1 = *(const f32x4*)(smem + ((hs * 256 + seg * 32 + 16) ^ fH));
    const int nbase = n0 + seg * 8;
    float mx = -INFINITY;
#pragma unroll
    for (int j = 0; j < 4; ++j) {
        if (nbase + j > eosb) v0[j] = -INFINITY;
        if (nbase + 4 + j > eosb) v1[j] = -INFINITY;
        mx = fmaxf(mx, fmaxf(v0[j], v1[j]));
    }
    *(f32x4*)&Lg[(size_t)bb * 65536 + hs * 1024 + nbase] = v0;
    *(f32x4*)&Lg[(size_t)bb * 65536 + hs * 1024 + nbase + 4] = v1;
#pragma unroll
    for (int off = 1; off < 8; off <<= 1) mx = fmaxf(mx, __shfl_xor(mx, off));
    float sl = 0.f;
    if (mx > -INFINITY) {
#pragma unroll
        for (int j = 0; j < 4; ++j) sl += __expf(v0[j] - mx) + __expf(v1[j] - mx);
    }
#pragma unroll
    for (int off = 1; off < 8; off <<= 1) sl += __shfl_xor(sl, off);
    if (seg == 0) {
        float2 st = {mx, sl};
        *(float2*)&partials[(size_t)(((bb * 16 + chunk) * 64) + hs) * 2] = st;
    }
}

__global__ __launch_bounds__(256, 3) void pv_kernel(const float* __restrict__ x,
                                                    const float* __restrict__ Lg,
                                                    const float* __restrict__ partials,
                                                    float* __restrict__ y) {
    __shared__ char smem[32768];
    char* Pl = smem;
    char* Xl = smem + 16384;
    const int t = threadIdx.x, l = t & 63, w = t >> 6;
    const int vid = (blockIdx.x & 7) * 96 + (blockIdx.x >> 3);
    const int b = vid / 24, rem = vid % 24;
    const int kc = rem % 12, nh = rem / 12;
    const int k0 = kc * 64, nbase = nh * 512;
    const int wrA = (w >> 1) * 32, wcB = (w & 1) * 32;
    const float* Lgb = Lg + (size_t)b * 65536;
    const float* xb = x + (size_t)b * 786432 + k0 + l;
    const int fK = ((l & 7) << 4) | (((l >> 3) & 1) << 3);
    const int r0 = t >> 3, r1 = 32 + (t >> 3);
    float m0r, i0r, m1r, i1r;
    {
        const float* pb = partials + (size_t)b * 2048;
        float m = -INFINITY, m2 = -INFINITY;
#pragma unroll
        for (int c = 0; c < 16; ++c) {
            m  = fmaxf(m,  pb[(c * 64 + r0) * 2]);
            m2 = fmaxf(m2, pb[(c * 64 + r1) * 2]);
        }
        float s = 0.f, s2 = 0.f;
#pragma unroll
        for (int c = 0; c < 16; ++c) {
            float2 p0 = *(const float2*)&pb[(c * 64 + r0) * 2];
            float2 p1 = *(const float2*)&pb[(c * 64 + r1) * 2];
            s  += p0.y * __expf(p0.x - m);
            s2 += p1.y * __expf(p1.x - m2);
        }
        m0r = m; i0r = 1.0f / s;
        m1r = m2; i1r = 1.0f / s2;
    }
    const int n0s0 = (((t & 7) ^ (r0 & 7)) * 8);
    const int n0s1 = (((t & 7) ^ (r1 & 7)) * 8);
    f32x4 acc[2][2];
#pragma unroll
    for (int i = 0; i < 2; ++i)
#pragma unroll
        for (int j = 0; j < 2; ++j) acc[i][j] = (f32x4)0.f;

    auto STAGE = [&](int bufb, int T) {
        const int nt_ = nbase + T * 64;
        f32x4 lo = *(const f32x4*)&Lgb[(size_t)r0 * 1024 + nt_ + n0s0];
        f32x4 hi = *(const f32x4*)&Lgb[(size_t)r0 * 1024 + nt_ + n0s0 + 4];
        f32x4 lo1 = *(const f32x4*)&Lgb[(size_t)r1 * 1024 + nt_ + n0s1];
        f32x4 hi1 = *(const f32x4*)&Lgb[(size_t)r1 * 1024 + nt_ + n0s1 + 4];
        float xv[16];
#pragma unroll
        for (int i_ = 0; i_ < 4; ++i_)
#pragma unroll
            for (int j_ = 0; j_ < 4; ++j_)
                xv[i_ * 4 + j_] = xb[(size_t)(nt_ + i_ * 16 + w * 4 + j_) * 768];
        bf16x8 pk;
#pragma unroll
        for (int j_ = 0; j_ < 4; ++j_) pk[j_]     = (__bf16)(__expf(lo[j_] - m0r) * i0r);
#pragma unroll
        for (int j_ = 0; j_ < 4; ++j_) pk[4 + j_] = (__bf16)(__expf(hi[j_] - m0r) * i0r);
        *(bf16x8*)(Pl + bufb * 8192 + t * 16) = pk;
#pragma unroll
        for (int j_ = 0; j_ < 4; ++j_) pk[j_]     = (__bf16)(__expf(lo1[j_] - m1r) * i1r);
#pragma unroll
        for (int j_ = 0; j_ < 4; ++j_) pk[4 + j_] = (__bf16)(__expf(hi1[j_] - m1r) * i1r);
        *(bf16x8*)(Pl + bufb * 8192 + 4096 + t * 16) = pk;
#pragma unroll
        for (int i_ = 0; i_ < 4; ++i_) {
            bf16x4 vv = {(__bf16)xv[i_ * 4 + 0], (__bf16)xv[i_ * 4 + 1],
                         (__bf16)xv[i_ * 4 + 2], (__bf16)xv[i_ * 4 + 3]};
            *(bf16x4*)(Xl + bufb * 8192 + ((l * 128 + (i_ * 16 + w * 4) * 2) ^ fK)) = vv;
        }
    };
    auto COMPUTE = [&](int bufb) {
#pragma unroll
        for (int kh = 0; kh < 2; ++kh) {
            const int u = kh * 4 + (l >> 4);
            bf16x8 af[2], bfr[2];
#pragma unroll
            for (int i = 0; i < 2; ++i) {
                const int row = wrA + i * 16 + (l & 15);
                af[i] = *(const bf16x8*)(Pl + bufb * 8192 +
                                         ((row * 128 + u * 16) ^ ((row & 7) << 4)));
            }
#pragma unroll
            for (int j = 0; j < 2; ++j) {
                const int kcol = wcB + j * 16 + (l & 15);
                const int fKc = ((kcol & 7) << 4) | (((kcol >> 3) & 1) << 3);
                const int addrA = kcol * 128 + kh * 64 + (l >> 4) * 16;
                u32x2 lo = *(const u32x2*)(Xl + bufb * 8192 + (addrA ^ fKc));
                u32x2 hi = *(const u32x2*)(Xl + bufb * 8192 + ((addrA + 8) ^ fKc));
                u32x4 uu = {lo[0], lo[1], hi[0], hi[1]};
                bfr[j] = __builtin_bit_cast(bf16x8, uu);
            }
#pragma unroll
            for (int i = 0; i < 2; ++i)
#pragma unroll
                for (int j = 0; j < 2; ++j)
                    acc[i][j] = __builtin_amdgcn_mfma_f32_16x16x32_bf16(
                        af[i], bfr[j], acc[i][j], 0, 0, 0);
        }
    };
    STAGE(0, 0);
    __syncthreads();
    int buf = 0;
    for (int step = 0; step < 8; ++step) {
        if (step + 1 < 8) STAGE(buf ^ 1, step + 1);
        COMPUTE(buf);
        __syncthreads();
        buf ^= 1;
    }
#pragma unroll
    for (int i = 0; i < 2; ++i)
#pragma unroll
        for (int j = 0; j < 2; ++j) {
            const int kcol = wcB + j * 16 + (l & 15);
#pragma unroll
            for (int r = 0; r < 4; ++r) {
                const int hs2 = wrA + i * 16 + (l >> 4) * 4 + r;
                *(float*)(smem + ((hs2 * 256 + kcol * 4) ^ ((hs2 & 7) << 4))) = acc[i][j][r];
            }
        }
    __syncthreads();
    float* yh = y + (size_t)nh * 1572864;
    const int hs2 = t >> 2;
#pragma unroll
    for (int i = 0; i < 4; ++i) {
        const int seg = (t & 3) + i * 4;
        f32x4 v = *(const f32x4*)(smem + ((hs2 * 256 + seg * 16) ^ ((hs2 & 7) << 4)));
        *(f32x4*)&yh[(size_t)(b * 64 + hs2) * 768 + k0 + seg * 4] = v;
    }
}

__global__ __launch_bounds__(256) void out_kernel(const float* __restrict__ y,
                                                  const float* __restrict__ wk,
                                                  const float* __restrict__ bk,
                                                  float* __restrict__ out) {
    __shared__ float ylds[8 * 768];
    __shared__ float red[2048];
    const int t = threadIdx.x;
    const int vid = (blockIdx.x & 7) * 32 + (blockIdx.x >> 3);
    const int h = vid >> 4, bp = vid & 15;
#pragma unroll
    for (int r = 0; r < 8; ++r) {
        const int gb = bp * 2 + (r >> 2);
        const int hs = h * 4 + (r & 3);
#pragma unroll
        for (int i = 0; i < 3; ++i) {
            const size_t idx = (size_t)(gb * 64 + hs) * 768 + i * 256 + t;
            ylds[r * 768 + i * 256 + t] = y[idx] + y[idx + 1572864];
        }
    }
    __syncthreads();
    const int kp = t >> 6, d = t & 63;
    float acc[8] = {0.f, 0.f, 0.f, 0.f, 0.f, 0.f, 0.f, 0.f};
    for (int i = 0; i < 48; ++i) {
        const int k = kp * 192 + i * 4;
        const float wv0 = wk[(size_t)(k + 0) * 1024 + h * 64 + d];
        const float wv1 = wk[(size_t)(k + 1) * 1024 + h * 64 + d];
        const float wv2 = wk[(size_t)(k + 2) * 1024 + h * 64 + d];
        const float wv3 = wk[(size_t)(k + 3) * 1024 + h * 64 + d];
#pragma unroll
        for (int r = 0; r < 8; ++r) {
            f32x4 yv = *(const f32x4*)&ylds[r * 768 + k];
            acc[r] += yv[0] * wv0 + yv[1] * wv1 + yv[2] * wv2 + yv[3] * wv3;
        }
    }
#pragma unroll
    for (int r = 0; r < 8; ++r) red[(r * 64 + d) * 4 + kp] = acc[r];
    __syncthreads();
#pragma unroll
    for (int i = 0; i < 2; ++i) {
        const int o = i * 256 + t;
        const int r = o >> 6, dd = o & 63;
        f32x4 pv = *(const f32x4*)&red[o * 4];
        const float s = pv[0] + pv[1] + pv[2] + pv[3] + bk[h * 64 + dd];
        const int gb = bp * 2 + (r >> 2);
        out[(size_t)(gb * 64 + h * 4 + (r & 3)) * 64 + dd] = s;
    }
}

// ---------------------------------------------------------------------------
extern "C" void kernel_launch(void* const* d_in, const int* in_sizes, int n_in,
                              void* d_out, int out_size, void* d_ws, size_t ws_size,
                              hipStream_t stream) {
    const float* x     = (const float*)d_in[0];   // (32,1024,768)
    const int*   eos   = (const int*)d_in[1];     // (32,)
    const float* q_emb = (const float*)d_in[2];   // (16,4,64)
    const float* Wk    = (const float*)d_in[3];   // (768,1024)
    const float* bk    = (const float*)d_in[4];   // (1024,)
    float* out = (float*)d_out;

    char* ws = (char*)d_ws;
    __bf16* qwT      = (__bf16*)ws;                 // 96 KB  [hs 64][k 768]
    float*  Lg       = (float*)(ws + 131072);       // 8 MB   [b][hs][n]
    float*  partials = (float*)(ws + 8519680);      // 256 KB [b][chunk 16][hs][2]
    float*  y        = (float*)(ws + 8781824);      // 12 MB  [nh 2][b][hs][k]

    void* args[] = {(void*)&x, (void*)&eos, (void*)&q_emb, (void*)&Wk, (void*)&bk,
                    (void*)&out, (void*)&qwT, (void*)&Lg, (void*)&partials, (void*)&y};
    hipError_t err = hipLaunchCooperativeKernel((const void*)fused_kernel,
                                                dim3(256), dim3(512), args, 0, stream);
    if (err != hipSuccess) {
        // validated 4-kernel fallback (identical ws layout)
        qw_kernel<<<dim3(12, 16), 256, 0, stream>>>(q_emb, Wk, qwT);
        logits_kernel<<<dim3(512), 512, 0, stream>>>(x, qwT, eos, Lg, partials);
        pv_kernel<<<dim3(768), 256, 0, stream>>>(x, Lg, partials, y);
        out_kernel<<<dim3(256), 256, 0, stream>>>(y, Wk, bk, out);
    }
}

// Round 9
// 66.299 us; speedup vs baseline: 4.9607x; 4.9607x over previous
//
#include <hip/hip_runtime.h>
#include <hip/hip_bf16.h>
#include <stdint.h>

typedef float  f32x4  __attribute__((ext_vector_type(4)));
typedef __bf16 bf16x4 __attribute__((ext_vector_type(4)));
typedef __bf16 bf16x8 __attribute__((ext_vector_type(8)));
typedef unsigned int u32x2 __attribute__((ext_vector_type(2)));
typedef unsigned int u32x4 __attribute__((ext_vector_type(4)));

#define AS1 __attribute__((address_space(1)))
#define AS3 __attribute__((address_space(3)))

__device__ __forceinline__ void async_load16(const void* g, void* lds) {
    __builtin_amdgcn_global_load_lds((const AS1 unsigned int*)g,
                                     (AS3 unsigned int*)lds, 16, 0, 0);
}

// ---------------------------------------------------------------------------
// K0: out[b][hs][d] = bk[h*64+d]   (bias init; pv atomically accumulates)
// ---------------------------------------------------------------------------
__global__ __launch_bounds__(256) void bias_init(const float* __restrict__ bk,
                                                 float* __restrict__ out) {
    const int idx = blockIdx.x * 256 + threadIdx.x;   // 512 blocks -> 131072
    out[idx] = bk[((idx >> 8) & 15) * 64 + (idx & 63)];
}

// ---------------------------------------------------------------------------
// K1: qw[hs][k] = scale * sum_d q[h,s,d] * Wk[k, h*64+d]   (bf16, [hs][768])
// ---------------------------------------------------------------------------
__global__ __launch_bounds__(256) void qw_kernel(const float* __restrict__ q_emb,
                                                 const float* __restrict__ wk,
                                                 __bf16* __restrict__ qwT) {
    __shared__ float qlds[256];
    __shared__ float part[4096];  // [k 64][s 4][dseg 16]
    const int t = threadIdx.x;
    const int kc = blockIdx.x;   // 0..11
    const int h  = blockIdx.y;   // 0..15
    const int k0 = kc * 64;
    qlds[t] = q_emb[h * 256 + t] * 0.125f;   // scale = D^-0.5 = 1/8
    __syncthreads();
    const int dseg = t & 15;
    const int krow = t >> 4;   // 0..15
#pragma unroll
    for (int i = 0; i < 4; ++i) {
        const int k = i * 16 + krow;
        f32x4 wv = *(const f32x4*)&wk[(size_t)(k0 + k) * 1024 + h * 64 + dseg * 4];
#pragma unroll
        for (int s = 0; s < 4; ++s) {
            float p = qlds[s * 64 + dseg * 4 + 0] * wv[0]
                    + qlds[s * 64 + dseg * 4 + 1] * wv[1]
                    + qlds[s * 64 + dseg * 4 + 2] * wv[2]
                    + qlds[s * 64 + dseg * 4 + 3] * wv[3];
            part[k * 64 + s * 16 + dseg] = p;
        }
    }
    __syncthreads();
    const int k = t >> 2, s = t & 3;
    const float* pp = &part[k * 64 + s * 16];
    float sum = 0.f;
#pragma unroll
    for (int j = 0; j < 16; ++j) sum += pp[j];
    qwT[(h * 4 + s) * 768 + k0 + k] = (__bf16)sum;
}

// ---------------------------------------------------------------------------
// K2: logits (bf16 out) + per-chunk softmax partials computed from the
// ROUNDED values (so pv's normalization is bit-consistent).
// BM=128 -> grid 256, 512 thr (8 waves, 4Mx2N).
// ---------------------------------------------------------------------------
__global__ __launch_bounds__(512) void logits_kernel(const float* __restrict__ x,
                                                     const __bf16* __restrict__ qwT,
                                                     const int* __restrict__ eos_idx,
                                                     __bf16* __restrict__ Lg,
                                                     float* __restrict__ partials) {
    __shared__ char smem[49152];
    char* Bl = smem;           // 2 x 8 KB  [col 64][k 64] bf16, XOR ((col&7)<<4)
    char* Al = smem + 16384;   // 2 x 16 KB [row 128][k 64] bf16, XOR ((row&7)<<4)
    const int t = threadIdx.x, l = t & 63, w = t >> 6;
    const int m0 = blockIdx.x * 128;
    const int bb = m0 >> 10, n0 = m0 & 1023;
    const int chunk = blockIdx.x & 7;
    const int wrA = (w >> 1) * 32;  // m(=n of attn) frag base
    const int wcB = (w & 1) * 32;   // hs base

    f32x4 acc[2][2];
#pragma unroll
    for (int i = 0; i < 2; ++i)
#pragma unroll
        for (int j = 0; j < 2; ++j) acc[i][j] = (f32x4)0.f;

    const int Bcol = t >> 3, Bseg = t & 7;
    const __bf16* qsrc = qwT + Bcol * 768 + (Bseg ^ (Bcol & 7)) * 8;
    const int Arow0 = t >> 4;   // + i*32
    const int Aseg = t & 15;

    f32x4 av[4];
    // ---- prologue (kt = 0)
    async_load16(qsrc, Bl + t * 16);
#pragma unroll
    for (int i = 0; i < 4; ++i)
        av[i] = *(const f32x4*)&x[(size_t)(m0 + i * 32 + Arow0) * 768 + Aseg * 4];
#pragma unroll
    for (int i = 0; i < 4; ++i) {
        const int row = i * 32 + Arow0;
        bf16x4 vv = {(__bf16)av[i][0], (__bf16)av[i][1], (__bf16)av[i][2], (__bf16)av[i][3]};
        *(bf16x4*)(Al + ((row * 128 + Aseg * 8) ^ ((row & 7) << 4))) = vv;
    }
    asm volatile("s_waitcnt vmcnt(0)" ::: "memory");
    __syncthreads();

    int buf = 0;
    for (int step = 0; step < 12; ++step) {
        const int nbuf = buf ^ 1;
        const bool more = (step + 1) < 12;
        if (more) {
            const int kt = (step + 1) * 64;
            async_load16(qsrc + kt, Bl + nbuf * 8192 + t * 16);
#pragma unroll
            for (int i = 0; i < 4; ++i)
                av[i] = *(const f32x4*)&x[(size_t)(m0 + i * 32 + Arow0) * 768 + kt + Aseg * 4];
        }
#pragma unroll
        for (int kh = 0; kh < 2; ++kh) {
            const int u = kh * 4 + (l >> 4);
            bf16x8 af[2], bfr[2];
#pragma unroll
            for (int i = 0; i < 2; ++i) {
                const int row = wrA + i * 16 + (l & 15);
                af[i] = *(const bf16x8*)(Al + buf * 16384 +
                                         ((row * 128 + u * 16) ^ ((row & 7) << 4)));
            }
#pragma unroll
            for (int j = 0; j < 2; ++j) {
                const int col = wcB + j * 16 + (l & 15);
                bfr[j] = *(const bf16x8*)(Bl + buf * 8192 +
                                          ((col * 128 + u * 16) ^ ((col & 7) << 4)));
            }
#pragma unroll
            for (int i = 0; i < 2; ++i)
#pragma unroll
                for (int j = 0; j < 2; ++j)
                    acc[i][j] = __builtin_amdgcn_mfma_f32_16x16x32_bf16(
                        af[i], bfr[j], acc[i][j], 0, 0, 0);
        }
        if (more) {
#pragma unroll
            for (int i = 0; i < 4; ++i) {
                const int row = i * 32 + Arow0;
                bf16x4 vv = {(__bf16)av[i][0], (__bf16)av[i][1], (__bf16)av[i][2], (__bf16)av[i][3]};
                *(bf16x4*)(Al + nbuf * 16384 + ((row * 128 + Aseg * 8) ^ ((row & 7) << 4))) = vv;
            }
        }
        asm volatile("s_waitcnt vmcnt(0)" ::: "memory");
        __syncthreads();
        buf = nbuf;
    }

    // ---- epilogue: frag -> LDS [hs 64][n 128] f32 -> mask, bf16-round,
    //      stats FROM ROUNDED values, bf16 store
#pragma unroll
    for (int i = 0; i < 2; ++i)
#pragma unroll
        for (int j = 0; j < 2; ++j) {
            const int hs = wcB + j * 16 + (l & 15);
            const int nb = wrA + i * 16 + (l >> 4) * 4;
            *(f32x4*)(smem + ((hs * 512 + nb * 4) ^ ((hs & 7) << 4))) = acc[i][j];
        }
    __syncthreads();
    const int eosb = eos_idx[bb];
    const int hs = t >> 3, seg7 = t & 7;
    const int fH = (hs & 7) << 4;
    float mx = -INFINITY;
    bf16x4 pk4[4];
#pragma unroll
    for (int i = 0; i < 4; ++i) {
        const int seg = seg7 + i * 8;
        f32x4 v = *(const f32x4*)(smem + ((hs * 512 + seg * 16) ^ fH));
        bf16x4 pk;
#pragma unroll
        for (int j = 0; j < 4; ++j) {
            const float f = (n0 + seg * 4 + j > eosb) ? -INFINITY : v[j];
            pk[j] = (__bf16)f;
            mx = fmaxf(mx, (float)pk[j]);
        }
        pk4[i] = pk;
        *(bf16x4*)&Lg[(size_t)bb * 65536 + hs * 1024 + n0 + seg * 4] = pk;
    }
#pragma unroll
    for (int off = 1; off < 8; off <<= 1) mx = fmaxf(mx, __shfl_xor(mx, off));
    float sl = 0.f;
    if (mx > -INFINITY) {
#pragma unroll
        for (int i = 0; i < 4; ++i)
#pragma unroll
            for (int j = 0; j < 4; ++j) sl += __expf((float)pk4[i][j] - mx);
    }
#pragma unroll
    for (int off = 1; off < 8; off <<= 1) sl += __shfl_xor(sl, off);
    if (seg7 == 0) {
        float2 st = {mx, sl};
        *(float2*)&partials[(size_t)(((bb * 8 + chunk) * 64) + hs) * 2] = st;
    }
}

// ---------------------------------------------------------------------------
// K3: pv + out fused.  Per (b,kc): y-slice[hs 64][k 64] via MFMA over n=1024,
// then out-partial[hs][d] = y_slice @ Wk[k0:,h*64+d] accumulated atomically.
// grid 384 = 32 b x 12 kc (XCD-swizzled), 256 thr, 16 steps.
// ---------------------------------------------------------------------------
__global__ __launch_bounds__(256, 3) void pv_kernel(const float* __restrict__ x,
                                                    const __bf16* __restrict__ Lg,
                                                    const float* __restrict__ partials,
                                                    const float* __restrict__ wk,
                                                    float* __restrict__ out_p) {
    __shared__ char smem[32768];
    char* Pl = smem;           // 2 x 8 KB  [hs 64][n 64] bf16, XOR ((row&7)<<4)
    char* Xl = smem + 16384;   // 2 x 8 KB  [k 64][n 64] bf16, XOR fK
    const int t = threadIdx.x, l = t & 63, w = t >> 6;
    const int vid = (blockIdx.x & 7) * 48 + (blockIdx.x >> 3);  // bijective XCD swizzle
    const int b = vid / 12, kc = vid % 12;
    const int k0 = kc * 64;
    const int wrA = (w >> 1) * 32, wcB = (w & 1) * 32;
    const __bf16* Lgb = Lg + (size_t)b * 65536;
    const float* xb = x + (size_t)b * 786432 + k0 + l;   // this thread's k-column
    const int fK = ((l & 7) << 4) | (((l >> 3) & 1) << 3);

    // ---- combine softmax partials (8 chunks) for this thread's two rows
    const int r0 = t >> 3, r1 = 32 + (t >> 3);
    float m0r, i0r, m1r, i1r;
    {
        const float* pb = partials + (size_t)b * 1024;  // [chunk 8][hs 64] float2
        float m = -INFINITY, m2 = -INFINITY;
#pragma unroll
        for (int c = 0; c < 8; ++c) {
            m  = fmaxf(m,  pb[(c * 64 + r0) * 2]);
            m2 = fmaxf(m2, pb[(c * 64 + r1) * 2]);
        }
        float s = 0.f, s2 = 0.f;
#pragma unroll
        for (int c = 0; c < 8; ++c) {
            float2 p0 = *(const float2*)&pb[(c * 64 + r0) * 2];
            float2 p1 = *(const float2*)&pb[(c * 64 + r1) * 2];
            s  += p0.y * __expf(p0.x - m);
            s2 += p1.y * __expf(p1.x - m2);
        }
        m0r = m; i0r = 1.0f / s;
        m1r = m2; i1r = 1.0f / s2;
    }
    const int n0s0 = (((t & 7) ^ (r0 & 7)) * 8);
    const int n0s1 = (((t & 7) ^ (r1 & 7)) * 8);

    f32x4 acc[2][2];
#pragma unroll
    for (int i = 0; i < 2; ++i)
#pragma unroll
        for (int j = 0; j < 2; ++j) acc[i][j] = (f32x4)0.f;

    auto STAGE = [&](int bufb, int T) {
        bf16x8 g0 = *(const bf16x8*)&Lgb[(size_t)r0 * 1024 + T * 64 + n0s0];
        bf16x8 g1 = *(const bf16x8*)&Lgb[(size_t)r1 * 1024 + T * 64 + n0s1];
        float xv[16];
#pragma unroll
        for (int i_ = 0; i_ < 4; ++i_)
#pragma unroll
            for (int j_ = 0; j_ < 4; ++j_)
                xv[i_ * 4 + j_] = xb[(size_t)(T * 64 + i_ * 16 + w * 4 + j_) * 768];
        bf16x8 pk;
#pragma unroll
        for (int j_ = 0; j_ < 8; ++j_)
            pk[j_] = (__bf16)(__expf((float)g0[j_] - m0r) * i0r);
        *(bf16x8*)(Pl + bufb * 8192 + t * 16) = pk;
#pragma unroll
        for (int j_ = 0; j_ < 8; ++j_)
            pk[j_] = (__bf16)(__expf((float)g1[j_] - m1r) * i1r);
        *(bf16x8*)(Pl + bufb * 8192 + 4096 + t * 16) = pk;
#pragma unroll
        for (int i_ = 0; i_ < 4; ++i_) {
            bf16x4 vv = {(__bf16)xv[i_ * 4 + 0], (__bf16)xv[i_ * 4 + 1],
                         (__bf16)xv[i_ * 4 + 2], (__bf16)xv[i_ * 4 + 3]};
            *(bf16x4*)(Xl + bufb * 8192 + ((l * 128 + (i_ * 16 + w * 4) * 2) ^ fK)) = vv;
        }
    };
    auto COMPUTE = [&](int bufb) {
#pragma unroll
        for (int kh = 0; kh < 2; ++kh) {
            const int u = kh * 4 + (l >> 4);
            bf16x8 af[2], bfr[2];
#pragma unroll
            for (int i = 0; i < 2; ++i) {
                const int row = wrA + i * 16 + (l & 15);
                af[i] = *(const bf16x8*)(Pl + bufb * 8192 +
                                         ((row * 128 + u * 16) ^ ((row & 7) << 4)));
            }
#pragma unroll
            for (int j = 0; j < 2; ++j) {
                const int kcol = wcB + j * 16 + (l & 15);
                const int fKc = ((kcol & 7) << 4) | (((kcol >> 3) & 1) << 3);
                const int addrA = kcol * 128 + kh * 64 + (l >> 4) * 16;
                u32x2 lo = *(const u32x2*)(Xl + bufb * 8192 + (addrA ^ fKc));
                u32x2 hi = *(const u32x2*)(Xl + bufb * 8192 + ((addrA + 8) ^ fKc));
                u32x4 uu = {lo[0], lo[1], hi[0], hi[1]};
                bfr[j] = __builtin_bit_cast(bf16x8, uu);
            }
#pragma unroll
            for (int i = 0; i < 2; ++i)
#pragma unroll
                for (int j = 0; j < 2; ++j)
                    acc[i][j] = __builtin_amdgcn_mfma_f32_16x16x32_bf16(
                        af[i], bfr[j], acc[i][j], 0, 0, 0);
        }
    };

    STAGE(0, 0);
    __syncthreads();
    int buf = 0;
    for (int step = 0; step < 16; ++step) {
        if (step + 1 < 16) STAGE(buf ^ 1, step + 1);
        COMPUTE(buf);
        __syncthreads();
        buf ^= 1;
    }

    // ---- y-slice -> LDS [hs 64][k 64] f32 (XOR-swizzled)
#pragma unroll
    for (int i = 0; i < 2; ++i)
#pragma unroll
        for (int j = 0; j < 2; ++j) {
            const int kcol = wcB + j * 16 + (l & 15);
#pragma unroll
            for (int r = 0; r < 4; ++r) {
                const int hs2 = wrA + i * 16 + (l >> 4) * 4 + r;
                *(float*)(smem + ((hs2 * 256 + kcol * 4) ^ ((hs2 & 7) << 4))) = acc[i][j][r];
            }
        }
    __syncthreads();

    // ---- out-partial: wave w handles heads w*4..w*4+3, lane = d.
    // LDS reads are broadcast (uniform addr); Wk loads coalesced across d.
    const int d = l;
#pragma unroll
    for (int hh = 0; hh < 4; ++hh) {
        const int h = w * 4 + hh;
        const float* wcol = &wk[(size_t)k0 * 1024 + h * 64 + d];
        float ao0 = 0.f, ao1 = 0.f, ao2 = 0.f, ao3 = 0.f;
#pragma unroll 4
        for (int kq = 0; kq < 16; ++kq) {
            const float wv0 = wcol[(size_t)(kq * 4 + 0) * 1024];
            const float wv1 = wcol[(size_t)(kq * 4 + 1) * 1024];
            const float wv2 = wcol[(size_t)(kq * 4 + 2) * 1024];
            const float wv3 = wcol[(size_t)(kq * 4 + 3) * 1024];
            const int hsb = h * 4;
            f32x4 y0 = *(const f32x4*)(smem + (((hsb + 0) * 256 + kq * 16) ^ (((hsb + 0) & 7) << 4)));
            f32x4 y1 = *(const f32x4*)(smem + (((hsb + 1) * 256 + kq * 16) ^ (((hsb + 1) & 7) << 4)));
            f32x4 y2 = *(const f32x4*)(smem + (((hsb + 2) * 256 + kq * 16) ^ (((hsb + 2) & 7) << 4)));
            f32x4 y3 = *(const f32x4*)(smem + (((hsb + 3) * 256 + kq * 16) ^ (((hsb + 3) & 7) << 4)));
            ao0 += y0[0] * wv0 + y0[1] * wv1 + y0[2] * wv2 + y0[3] * wv3;
            ao1 += y1[0] * wv0 + y1[1] * wv1 + y1[2] * wv2 + y1[3] * wv3;
            ao2 += y2[0] * wv0 + y2[1] * wv1 + y2[2] * wv2 + y2[3] * wv3;
            ao3 += y3[0] * wv0 + y3[1] * wv1 + y3[2] * wv2 + y3[3] * wv3;
        }
        float* ob = &out_p[(size_t)(b * 64 + h * 4) * 64 + d];
        atomicAdd(ob +   0, ao0);
        atomicAdd(ob +  64, ao1);
        atomicAdd(ob + 128, ao2);
        atomicAdd(ob + 192, ao3);
    }
}

// ---------------------------------------------------------------------------
extern "C" void kernel_launch(void* const* d_in, const int* in_sizes, int n_in,
                              void* d_out, int out_size, void* d_ws, size_t ws_size,
                              hipStream_t stream) {
    const float* x     = (const float*)d_in[0];   // (32,1024,768)
    const int*   eos   = (const int*)d_in[1];     // (32,)
    const float* q_emb = (const float*)d_in[2];   // (16,4,64)
    const float* Wk    = (const float*)d_in[3];   // (768,1024)
    const float* bk    = (const float*)d_in[4];   // (1024,)
    float* out = (float*)d_out;

    char* ws = (char*)d_ws;
    __bf16* qwT      = (__bf16*)ws;                     // 96 KB  [hs 64][k 768]
    __bf16* Lg       = (__bf16*)(ws + 131072);          // 4 MB   [b][hs][n] bf16
    float*  partials = (float*)(ws + 131072 + 4194304); // 128 KB [b][chunk 8][hs][2]

    bias_init<<<dim3(512), 256, 0, stream>>>(bk, out);
    qw_kernel<<<dim3(12, 16), 256, 0, stream>>>(q_emb, Wk, qwT);
    logits_kernel<<<dim3(256), 512, 0, stream>>>(x, qwT, eos, Lg, partials);
    pv_kernel<<<dim3(384), 256, 0, stream>>>(x, Lg, partials, Wk, out);
}

// Round 10
// 63.763 us; speedup vs baseline: 5.1580x; 1.0398x over previous
//
#include <hip/hip_runtime.h>
#include <hip/hip_bf16.h>
#include <stdint.h>

typedef float  f32x4  __attribute__((ext_vector_type(4)));
typedef __bf16 bf16x4 __attribute__((ext_vector_type(4)));
typedef __bf16 bf16x8 __attribute__((ext_vector_type(8)));
typedef unsigned int u32x2 __attribute__((ext_vector_type(2)));
typedef unsigned int u32x4 __attribute__((ext_vector_type(4)));

#define AS1 __attribute__((address_space(1)))
#define AS3 __attribute__((address_space(3)))

__device__ __forceinline__ void async_load16(const void* g, void* lds) {
    __builtin_amdgcn_global_load_lds((const AS1 unsigned int*)g,
                                     (AS3 unsigned int*)lds, 16, 0, 0);
}

// ---------------------------------------------------------------------------
// K1: qw[hs][k] = scale * sum_d q[h,s,d] * Wk[k, h*64+d]   (bf16, [hs][768])
// ---------------------------------------------------------------------------
__global__ __launch_bounds__(256) void qw_kernel(const float* __restrict__ q_emb,
                                                 const float* __restrict__ wk,
                                                 __bf16* __restrict__ qwT) {
    __shared__ float qlds[256];
    __shared__ float part[4096];  // [k 64][s 4][dseg 16]
    const int t = threadIdx.x;
    const int kc = blockIdx.x;   // 0..11
    const int h  = blockIdx.y;   // 0..15
    const int k0 = kc * 64;
    qlds[t] = q_emb[h * 256 + t] * 0.125f;   // scale = D^-0.5 = 1/8
    __syncthreads();
    const int dseg = t & 15;
    const int krow = t >> 4;   // 0..15
#pragma unroll
    for (int i = 0; i < 4; ++i) {
        const int k = i * 16 + krow;
        f32x4 wv = *(const f32x4*)&wk[(size_t)(k0 + k) * 1024 + h * 64 + dseg * 4];
#pragma unroll
        for (int s = 0; s < 4; ++s) {
            float p = qlds[s * 64 + dseg * 4 + 0] * wv[0]
                    + qlds[s * 64 + dseg * 4 + 1] * wv[1]
                    + qlds[s * 64 + dseg * 4 + 2] * wv[2]
                    + qlds[s * 64 + dseg * 4 + 3] * wv[3];
            part[k * 64 + s * 16 + dseg] = p;
        }
    }
    __syncthreads();
    const int k = t >> 2, s = t & 3;
    const float* pp = &part[k * 64 + s * 16];
    float sum = 0.f;
#pragma unroll
    for (int j = 0; j < 16; ++j) sum += pp[j];
    qwT[(h * 4 + s) * 768 + k0 + k] = (__bf16)sum;
}

// ---------------------------------------------------------------------------
// K2: logits (bf16 out) + per-chunk softmax partials computed from the
// ROUNDED values (pv normalization bit-consistent). BM=128 -> grid 256.
// ---------------------------------------------------------------------------
__global__ __launch_bounds__(512) void logits_kernel(const float* __restrict__ x,
                                                     const __bf16* __restrict__ qwT,
                                                     const int* __restrict__ eos_idx,
                                                     __bf16* __restrict__ Lg,
                                                     float* __restrict__ partials) {
    __shared__ char smem[49152];
    char* Bl = smem;           // 2 x 8 KB  [col 64][k 64] bf16, XOR ((col&7)<<4)
    char* Al = smem + 16384;   // 2 x 16 KB [row 128][k 64] bf16, XOR ((row&7)<<4)
    const int t = threadIdx.x, l = t & 63, w = t >> 6;
    const int m0 = blockIdx.x * 128;
    const int bb = m0 >> 10, n0 = m0 & 1023;
    const int chunk = blockIdx.x & 7;
    const int wrA = (w >> 1) * 32;  // m(=n of attn) frag base
    const int wcB = (w & 1) * 32;   // hs base

    f32x4 acc[2][2];
#pragma unroll
    for (int i = 0; i < 2; ++i)
#pragma unroll
        for (int j = 0; j < 2; ++j) acc[i][j] = (f32x4)0.f;

    const int Bcol = t >> 3, Bseg = t & 7;
    const __bf16* qsrc = qwT + Bcol * 768 + (Bseg ^ (Bcol & 7)) * 8;
    const int Arow0 = t >> 4;   // + i*32
    const int Aseg = t & 15;

    f32x4 av[4];
    // ---- prologue (kt = 0)
    async_load16(qsrc, Bl + t * 16);
#pragma unroll
    for (int i = 0; i < 4; ++i)
        av[i] = *(const f32x4*)&x[(size_t)(m0 + i * 32 + Arow0) * 768 + Aseg * 4];
#pragma unroll
    for (int i = 0; i < 4; ++i) {
        const int row = i * 32 + Arow0;
        bf16x4 vv = {(__bf16)av[i][0], (__bf16)av[i][1], (__bf16)av[i][2], (__bf16)av[i][3]};
        *(bf16x4*)(Al + ((row * 128 + Aseg * 8) ^ ((row & 7) << 4))) = vv;
    }
    asm volatile("s_waitcnt vmcnt(0)" ::: "memory");
    __syncthreads();

    int buf = 0;
    for (int step = 0; step < 12; ++step) {
        const int nbuf = buf ^ 1;
        const bool more = (step + 1) < 12;
        if (more) {
            const int kt = (step + 1) * 64;
            async_load16(qsrc + kt, Bl + nbuf * 8192 + t * 16);
#pragma unroll
            for (int i = 0; i < 4; ++i)
                av[i] = *(const f32x4*)&x[(size_t)(m0 + i * 32 + Arow0) * 768 + kt + Aseg * 4];
        }
#pragma unroll
        for (int kh = 0; kh < 2; ++kh) {
            const int u = kh * 4 + (l >> 4);
            bf16x8 af[2], bfr[2];
#pragma unroll
            for (int i = 0; i < 2; ++i) {
                const int row = wrA + i * 16 + (l & 15);
                af[i] = *(const bf16x8*)(Al + buf * 16384 +
                                         ((row * 128 + u * 16) ^ ((row & 7) << 4)));
            }
#pragma unroll
            for (int j = 0; j < 2; ++j) {
                const int col = wcB + j * 16 + (l & 15);
                bfr[j] = *(const bf16x8*)(Bl + buf * 8192 +
                                          ((col * 128 + u * 16) ^ ((col & 7) << 4)));
            }
#pragma unroll
            for (int i = 0; i < 2; ++i)
#pragma unroll
                for (int j = 0; j < 2; ++j)
                    acc[i][j] = __builtin_amdgcn_mfma_f32_16x16x32_bf16(
                        af[i], bfr[j], acc[i][j], 0, 0, 0);
        }
        if (more) {
#pragma unroll
            for (int i = 0; i < 4; ++i) {
                const int row = i * 32 + Arow0;
                bf16x4 vv = {(__bf16)av[i][0], (__bf16)av[i][1], (__bf16)av[i][2], (__bf16)av[i][3]};
                *(bf16x4*)(Al + nbuf * 16384 + ((row * 128 + Aseg * 8) ^ ((row & 7) << 4))) = vv;
            }
        }
        asm volatile("s_waitcnt vmcnt(0)" ::: "memory");
        __syncthreads();
        buf = nbuf;
    }

    // ---- epilogue: frag -> LDS [hs 64][n 128] f32 -> mask, bf16-round,
    //      stats FROM ROUNDED values, bf16 store
#pragma unroll
    for (int i = 0; i < 2; ++i)
#pragma unroll
        for (int j = 0; j < 2; ++j) {
            const int hs = wcB + j * 16 + (l & 15);
            const int nb = wrA + i * 16 + (l >> 4) * 4;
            *(f32x4*)(smem + ((hs * 512 + nb * 4) ^ ((hs & 7) << 4))) = acc[i][j];
        }
    __syncthreads();
    const int eosb = eos_idx[bb];
    const int hs = t >> 3, seg7 = t & 7;
    const int fH = (hs & 7) << 4;
    float mx = -INFINITY;
    bf16x4 pk4[4];
#pragma unroll
    for (int i = 0; i < 4; ++i) {
        const int seg = seg7 + i * 8;
        f32x4 v = *(const f32x4*)(smem + ((hs * 512 + seg * 16) ^ fH));
        bf16x4 pk;
#pragma unroll
        for (int j = 0; j < 4; ++j) {
            const float f = (n0 + seg * 4 + j > eosb) ? -INFINITY : v[j];
            pk[j] = (__bf16)f;
            mx = fmaxf(mx, (float)pk[j]);
        }
        pk4[i] = pk;
        *(bf16x4*)&Lg[(size_t)bb * 65536 + hs * 1024 + n0 + seg * 4] = pk;
    }
#pragma unroll
    for (int off = 1; off < 8; off <<= 1) mx = fmaxf(mx, __shfl_xor(mx, off));
    float sl = 0.f;
    if (mx > -INFINITY) {
#pragma unroll
        for (int i = 0; i < 4; ++i)
#pragma unroll
            for (int j = 0; j < 4; ++j) sl += __expf((float)pk4[i][j] - mx);
    }
#pragma unroll
    for (int off = 1; off < 8; off <<= 1) sl += __shfl_xor(sl, off);
    if (seg7 == 0) {
        float2 st = {mx, sl};
        *(float2*)&partials[(size_t)(((bb * 8 + chunk) * 64) + hs) * 2] = st;
    }
}

// ---------------------------------------------------------------------------
// K3: y[b][hs][k] = sum_n softmax(Lg)[b,hs,n] * x[b,n,k]
// grid 384 = 32 b x 12 kc (XCD-swizzled), 256 thr, 16 n-steps, full n.
// ---------------------------------------------------------------------------
__global__ __launch_bounds__(256, 3) void pv_kernel(const float* __restrict__ x,
                                                    const __bf16* __restrict__ Lg,
                                                    const float* __restrict__ partials,
                                                    float* __restrict__ y) {
    __shared__ char smem[32768];
    char* Pl = smem;           // 2 x 8 KB  [hs 64][n 64] bf16, XOR ((row&7)<<4)
    char* Xl = smem + 16384;   // 2 x 8 KB  [k 64][n 64] bf16, XOR fK
    const int t = threadIdx.x, l = t & 63, w = t >> 6;
    const int vid = (blockIdx.x & 7) * 48 + (blockIdx.x >> 3);  // bijective XCD swizzle
    const int b = vid / 12, kc = vid % 12;
    const int k0 = kc * 64;
    const int wrA = (w >> 1) * 32, wcB = (w & 1) * 32;
    const __bf16* Lgb = Lg + (size_t)b * 65536;
    const float* xb = x + (size_t)b * 786432 + k0 + l;   // this thread's k-column
    const int fK = ((l & 7) << 4) | (((l >> 3) & 1) << 3);

    // ---- combine softmax partials (8 chunks) for this thread's two rows
    const int r0 = t >> 3, r1 = 32 + (t >> 3);
    float m0r, i0r, m1r, i1r;
    {
        const float* pb = partials + (size_t)b * 1024;  // [chunk 8][hs 64] float2
        float m = -INFINITY, m2 = -INFINITY;
#pragma unroll
        for (int c = 0; c < 8; ++c) {
            m  = fmaxf(m,  pb[(c * 64 + r0) * 2]);
            m2 = fmaxf(m2, pb[(c * 64 + r1) * 2]);
        }
        float s = 0.f, s2 = 0.f;
#pragma unroll
        for (int c = 0; c < 8; ++c) {
            float2 p0 = *(const float2*)&pb[(c * 64 + r0) * 2];
            float2 p1 = *(const float2*)&pb[(c * 64 + r1) * 2];
            s  += p0.y * __expf(p0.x - m);
            s2 += p1.y * __expf(p1.x - m2);
        }
        m0r = m; i0r = 1.0f / s;
        m1r = m2; i1r = 1.0f / s2;
    }
    const int n0s0 = (((t & 7) ^ (r0 & 7)) * 8);
    const int n0s1 = (((t & 7) ^ (r1 & 7)) * 8);

    f32x4 acc[2][2];
#pragma unroll
    for (int i = 0; i < 2; ++i)
#pragma unroll
        for (int j = 0; j < 2; ++j) acc[i][j] = (f32x4)0.f;

    auto STAGE = [&](int bufb, int T) {
        bf16x8 g0 = *(const bf16x8*)&Lgb[(size_t)r0 * 1024 + T * 64 + n0s0];
        bf16x8 g1 = *(const bf16x8*)&Lgb[(size_t)r1 * 1024 + T * 64 + n0s1];
        float xv[16];
#pragma unroll
        for (int i_ = 0; i_ < 4; ++i_)
#pragma unroll
            for (int j_ = 0; j_ < 4; ++j_)
                xv[i_ * 4 + j_] = xb[(size_t)(T * 64 + i_ * 16 + w * 4 + j_) * 768];
        bf16x8 pk;
#pragma unroll
        for (int j_ = 0; j_ < 8; ++j_)
            pk[j_] = (__bf16)(__expf((float)g0[j_] - m0r) * i0r);
        *(bf16x8*)(Pl + bufb * 8192 + t * 16) = pk;
#pragma unroll
        for (int j_ = 0; j_ < 8; ++j_)
            pk[j_] = (__bf16)(__expf((float)g1[j_] - m1r) * i1r);
        *(bf16x8*)(Pl + bufb * 8192 + 4096 + t * 16) = pk;
#pragma unroll
        for (int i_ = 0; i_ < 4; ++i_) {
            bf16x4 vv = {(__bf16)xv[i_ * 4 + 0], (__bf16)xv[i_ * 4 + 1],
                         (__bf16)xv[i_ * 4 + 2], (__bf16)xv[i_ * 4 + 3]};
            *(bf16x4*)(Xl + bufb * 8192 + ((l * 128 + (i_ * 16 + w * 4) * 2) ^ fK)) = vv;
        }
    };
    auto COMPUTE = [&](int bufb) {
#pragma unroll
        for (int kh = 0; kh < 2; ++kh) {
            const int u = kh * 4 + (l >> 4);
            bf16x8 af[2], bfr[2];
#pragma unroll
            for (int i = 0; i < 2; ++i) {
                const int row = wrA + i * 16 + (l & 15);
                af[i] = *(const bf16x8*)(Pl + bufb * 8192 +
                                         ((row * 128 + u * 16) ^ ((row & 7) << 4)));
            }
#pragma unroll
            for (int j = 0; j < 2; ++j) {
                const int kcol = wcB + j * 16 + (l & 15);
                const int fKc = ((kcol & 7) << 4) | (((kcol >> 3) & 1) << 3);
                const int addrA = kcol * 128 + kh * 64 + (l >> 4) * 16;
                u32x2 lo = *(const u32x2*)(Xl + bufb * 8192 + (addrA ^ fKc));
                u32x2 hi = *(const u32x2*)(Xl + bufb * 8192 + ((addrA + 8) ^ fKc));
                u32x4 uu = {lo[0], lo[1], hi[0], hi[1]};
                bfr[j] = __builtin_bit_cast(bf16x8, uu);
            }
#pragma unroll
            for (int i = 0; i < 2; ++i)
#pragma unroll
                for (int j = 0; j < 2; ++j)
                    acc[i][j] = __builtin_amdgcn_mfma_f32_16x16x32_bf16(
                        af[i], bfr[j], acc[i][j], 0, 0, 0);
        }
    };

    STAGE(0, 0);
    __syncthreads();
    int buf = 0;
    for (int step = 0; step < 16; ++step) {
        if (step + 1 < 16) STAGE(buf ^ 1, step + 1);
        COMPUTE(buf);
        __syncthreads();
        buf ^= 1;
    }

    // ---- epilogue: frag -> LDS [hs 64][k 64] f32 -> coalesced y store
#pragma unroll
    for (int i = 0; i < 2; ++i)
#pragma unroll
        for (int j = 0; j < 2; ++j) {
            const int kcol = wcB + j * 16 + (l & 15);
#pragma unroll
            for (int r = 0; r < 4; ++r) {
                const int hs2 = wrA + i * 16 + (l >> 4) * 4 + r;
                *(float*)(smem + ((hs2 * 256 + kcol * 4) ^ ((hs2 & 7) << 4))) = acc[i][j][r];
            }
        }
    __syncthreads();
    const int hs2 = t >> 2;
#pragma unroll
    for (int i = 0; i < 4; ++i) {
        const int seg = (t & 3) + i * 4;
        f32x4 v = *(const f32x4*)(smem + ((hs2 * 256 + seg * 16) ^ ((hs2 & 7) << 4)));
        *(f32x4*)&y[(size_t)(b * 64 + hs2) * 768 + k0 + seg * 4] = v;
    }
}

// ---------------------------------------------------------------------------
// K4: out[b][hs][d] = sum_k y[b,hs,k]*Wk[k,h*64+d] + bk[h*64+d]
// 256 blocks = (h 16) x (b-pair 16), 256 thr = 4 k-partitions x 64 d.
// ---------------------------------------------------------------------------
__global__ __launch_bounds__(256) void out_kernel(const float* __restrict__ y,
                                                  const float* __restrict__ wk,
                                                  const float* __restrict__ bk,
                                                  float* __restrict__ out) {
    __shared__ float ylds[8 * 768];  // 24 KB
    __shared__ float red[2048];      // 8 KB
    const int t = threadIdx.x;
    const int vid = (blockIdx.x & 7) * 32 + (blockIdx.x >> 3);  // same-h grouped per XCD
    const int h = vid >> 4, bp = vid & 15;
#pragma unroll
    for (int r = 0; r < 8; ++r) {
        const int gb = bp * 2 + (r >> 2);
        const int hs = h * 4 + (r & 3);
#pragma unroll
        for (int i = 0; i < 3; ++i)
            ylds[r * 768 + i * 256 + t] = y[(size_t)(gb * 64 + hs) * 768 + i * 256 + t];
    }
    __syncthreads();
    const int kp = t >> 6, d = t & 63;
    float acc[8] = {0.f, 0.f, 0.f, 0.f, 0.f, 0.f, 0.f, 0.f};
    for (int i = 0; i < 48; ++i) {
        const int k = kp * 192 + i * 4;
        const float wv0 = wk[(size_t)(k + 0) * 1024 + h * 64 + d];
        const float wv1 = wk[(size_t)(k + 1) * 1024 + h * 64 + d];
        const float wv2 = wk[(size_t)(k + 2) * 1024 + h * 64 + d];
        const float wv3 = wk[(size_t)(k + 3) * 1024 + h * 64 + d];
#pragma unroll
        for (int r = 0; r < 8; ++r) {
            f32x4 yv = *(const f32x4*)&ylds[r * 768 + k];
            acc[r] += yv[0] * wv0 + yv[1] * wv1 + yv[2] * wv2 + yv[3] * wv3;
        }
    }
#pragma unroll
    for (int r = 0; r < 8; ++r) red[(r * 64 + d) * 4 + kp] = acc[r];
    __syncthreads();
#pragma unroll
    for (int i = 0; i < 2; ++i) {
        const int o = i * 256 + t;
        const int r = o >> 6, dd = o & 63;
        f32x4 pv = *(const f32x4*)&red[o * 4];
        const float s = pv[0] + pv[1] + pv[2] + pv[3] + bk[h * 64 + dd];
        const int gb = bp * 2 + (r >> 2);
        out[(size_t)(gb * 64 + h * 4 + (r & 3)) * 64 + dd] = s;
    }
}

// ---------------------------------------------------------------------------
extern "C" void kernel_launch(void* const* d_in, const int* in_sizes, int n_in,
                              void* d_out, int out_size, void* d_ws, size_t ws_size,
                              hipStream_t stream) {
    const float* x     = (const float*)d_in[0];   // (32,1024,768)
    const int*   eos   = (const int*)d_in[1];     // (32,)
    const float* q_emb = (const float*)d_in[2];   // (16,4,64)
    const float* Wk    = (const float*)d_in[3];   // (768,1024)
    const float* bk    = (const float*)d_in[4];   // (1024,)
    float* out = (float*)d_out;

    char* ws = (char*)d_ws;
    __bf16* qwT      = (__bf16*)ws;                      // 96 KB  [hs 64][k 768]
    __bf16* Lg       = (__bf16*)(ws + 131072);           // 4 MB   [b][hs][n] bf16
    float*  partials = (float*)(ws + 4325376);           // 128 KB [b][chunk 8][hs][2]
    float*  y        = (float*)(ws + 4456448);           // 6 MB   [b][hs][k]

    qw_kernel<<<dim3(12, 16), 256, 0, stream>>>(q_emb, Wk, qwT);
    logits_kernel<<<dim3(256), 512, 0, stream>>>(x, qwT, eos, Lg, partials);
    pv_kernel<<<dim3(384), 256, 0, stream>>>(x, Lg, partials, y);
    out_kernel<<<dim3(256), 256, 0, stream>>>(y, Wk, bk, out);
}